// Round 5
// baseline (506.882 us; speedup 1.0000x reference)
//
#include <hip/hip_runtime.h>
#include <math.h>

// B=2, H=W=64, N=4096, C=128, K=8, 5 Sinkhorn iters. S is fp32 (selection-critical).
#define UVS 4104   // padded u/v batch stride

// Workspace layout (float offsets)
#define OFF_U     33554432ul               // 2*4096*4096 floats of S first
#define OFF_V     (OFF_U + 2*UVS)
#define OFF_RN    (OFF_V + 2*UVS)          // 16384 (rnA | rnB)
#define OFF_PARTS (OFF_RN + 16384)         // 2*512*4096 column partial sums (A_j per 8-row chunk)
#define OFF_TKV   (OFF_PARTS + 4194304)    // 2*4096*8
#define OFF_TKP   (OFF_TKV + 65536)        // 2*4096*8*2
#define OFF_DP    (OFF_TKP + 131072)       // 2*8*2*4096 planar
#define OFF_GEO   (OFF_DP + 131072)        // 2*4096*8
#define OFF_SUM   (OFF_GEO + 65536)        // 24 doubles

#define NORMC   (-9.010913348f)            // -log(8192)
#define MLOG2   (-0.6931471806f)           // log(N)+NORMC = -log(2)

typedef __attribute__((ext_vector_type(8))) short bf16x8;
typedef __attribute__((ext_vector_type(4))) float f32x4;

static __device__ __forceinline__ unsigned f2bf(float x) {  // RTNE fp32->bf16 bits
    unsigned u = __float_as_uint(x);
    return (u + 0x7FFFu + ((u >> 16) & 1u)) >> 16;
}
static __device__ __forceinline__ float bf2f(unsigned h) { return __uint_as_float(h << 16); }

// --- 1) inverse L2 norms ---
__global__ __launch_bounds__(256) void norms_kernel(
    const float* __restrict__ fA, const float* __restrict__ fB, float* __restrict__ rn)
{
    int t = threadIdx.x;
    int rowg = blockIdx.x * 4 + (t >> 6);
    int lane = t & 63;
    const float* f = (rowg < 8192) ? fA : fB;
    int r = rowg & 8191;
    float x0 = f[(size_t)r * 128 + lane];
    float x1 = f[(size_t)r * 128 + 64 + lane];
    float s = x0 * x0 + x1 * x1;
    #pragma unroll
    for (int off = 32; off > 0; off >>= 1) s += __shfl_xor(s, off, 64);
    if (lane == 0) rn[rowg] = 1.f / fmaxf(sqrtf(s), 1e-12f);
}

// --- 2) S = (fA.fB^T)*rnA*rnB/temp via bf16 hi/lo-split MFMA; fp32 output ---
#define LDK 72
__global__ __launch_bounds__(256) void gemm_mfma(
    const float* __restrict__ fA, const float* __restrict__ fB,
    const float* __restrict__ rn, const float* __restrict__ temp,
    float* __restrict__ S)
{
    __shared__ short Ahi[64 * LDK], Alo[64 * LDK], Bhi[64 * LDK], Blo[64 * LDK];
    int b = blockIdx.z;
    int i0 = blockIdx.y * 64, j0 = blockIdx.x * 64;
    int t = threadIdx.x;
    int r = t >> 2;
    int c0 = (t & 3) * 16;
    int wave = t >> 6, lane = t & 63;
    int fr = lane & 15;
    int quad = lane >> 4;
    f32x4 acc[4] = {f32x4{0,0,0,0}, f32x4{0,0,0,0}, f32x4{0,0,0,0}, f32x4{0,0,0,0}};

    const float* pa0 = fA + ((size_t)(b * 4096 + i0 + r)) * 128 + c0;
    const float* pb0 = fB + ((size_t)(b * 4096 + j0 + r)) * 128 + c0;

    for (int ks = 0; ks < 2; ks++) {
        float4 a4[4], b4[4];
        #pragma unroll
        for (int q = 0; q < 4; q++) {
            a4[q] = *(const float4*)(pa0 + ks * 64 + q * 4);
            b4[q] = *(const float4*)(pb0 + ks * 64 + q * 4);
        }
        __syncthreads();
        #pragma unroll
        for (int q = 0; q < 4; q++) {
            float xv[4] = {a4[q].x, a4[q].y, a4[q].z, a4[q].w};
            unsigned h[4], l[4];
            #pragma unroll
            for (int e = 0; e < 4; e++) { h[e] = f2bf(xv[e]); l[e] = f2bf(xv[e] - bf2f(h[e])); }
            *(uint2*)&Ahi[r * LDK + c0 + q * 4] = make_uint2(h[0] | (h[1] << 16), h[2] | (h[3] << 16));
            *(uint2*)&Alo[r * LDK + c0 + q * 4] = make_uint2(l[0] | (l[1] << 16), l[2] | (l[3] << 16));
            float yv[4] = {b4[q].x, b4[q].y, b4[q].z, b4[q].w};
            #pragma unroll
            for (int e = 0; e < 4; e++) { h[e] = f2bf(yv[e]); l[e] = f2bf(yv[e] - bf2f(h[e])); }
            *(uint2*)&Bhi[r * LDK + c0 + q * 4] = make_uint2(h[0] | (h[1] << 16), h[2] | (h[3] << 16));
            *(uint2*)&Blo[r * LDK + c0 + q * 4] = make_uint2(l[0] | (l[1] << 16), l[2] | (l[3] << 16));
        }
        __syncthreads();
        #pragma unroll
        for (int kk = 0; kk < 2; kk++) {
            int koff = kk * 32 + quad * 8;
            bf16x8 ah = *(const bf16x8*)&Ahi[(wave * 16 + fr) * LDK + koff];
            bf16x8 al = *(const bf16x8*)&Alo[(wave * 16 + fr) * LDK + koff];
            #pragma unroll
            for (int nb = 0; nb < 4; nb++) {
                bf16x8 bh = *(const bf16x8*)&Bhi[(nb * 16 + fr) * LDK + koff];
                bf16x8 bl = *(const bf16x8*)&Blo[(nb * 16 + fr) * LDK + koff];
                acc[nb] = __builtin_amdgcn_mfma_f32_16x16x32_bf16(ah, bh, acc[nb], 0, 0, 0);
                acc[nb] = __builtin_amdgcn_mfma_f32_16x16x32_bf16(al, bh, acc[nb], 0, 0, 0);
                acc[nb] = __builtin_amdgcn_mfma_f32_16x16x32_bf16(ah, bl, acc[nb], 0, 0, 0);
            }
        }
    }
    float invt = 1.f / temp[0];
    int m0 = i0 + wave * 16 + quad * 4;
    float ra[4];
    #pragma unroll
    for (int rr = 0; rr < 4; rr++) ra[rr] = rn[b * 4096 + m0 + rr] * invt;
    #pragma unroll
    for (int nb = 0; nb < 4; nb++) {
        int col = j0 + nb * 16 + fr;
        float rbv = rn[8192 + b * 4096 + col];
        #pragma unroll
        for (int rr = 0; rr < 4; rr++)
            S[((size_t)(b * 4096 + m0 + rr)) * 4096 + col] = acc[nb][rr] * (ra[rr] * rbv);
    }
}

// --- 3) fused Sinkhorn iteration, register-resident, exp-factorized ---
// grid (512 chunks, 1, 2 batches); block 256; chunk = 8 rows (2 stages x 4 rows).
// E' = exp(S+v_old) computed ONCE per element; col partial A_j = sum_i E'*e^{u_i};
// true colsum_j = e^{-v_old_j} * A_j (factor applied in sink_vB).
__global__ __launch_bounds__(256) void sink_fused(
    const float* __restrict__ S, float* __restrict__ u, const float* __restrict__ v,
    const float* __restrict__ dbp, float* __restrict__ parts)
{
    int b = blockIdx.z;
    int ch = blockIdx.x;          // 0..511
    int t = threadIdx.x;
    int wave = t >> 6, lane = t & 63;
    const float* vb = v + b * UVS;
    float db = dbp[0];
    __shared__ float part[4 * 256];
    __shared__ float eu4[4];

    // chunk 0 also refreshes the dustbin-row dual uN (uses OLD v)
    if (ch == 0) {
        __shared__ float red[256];
        float sv = 0.f;
        #pragma unroll
        for (int k = 0; k < 16; k++) sv += __expf(vb[t + k * 256]);
        red[t] = sv; __syncthreads();
        for (int off = 128; off > 0; off >>= 1) {
            if (t < off) red[t] += red[t + off];
            __syncthreads();
        }
        if (t == 0) u[b * UVS + 4096] = MLOG2 - __logf(__expf(db) * red[0] + __expf(vb[4096]));
        __syncthreads();
    }

    float dtail = __expf(db + vb[4096]);
    // hoist this thread's 16 v values (columns c*1024 + t*4 .. +3)
    float4 vr[4];
    #pragma unroll
    for (int c = 0; c < 4; c++) vr[c] = *(const float4*)(vb + c * 1024 + t * 4);

    float colacc[16];
    #pragma unroll
    for (int k = 0; k < 16; k++) colacc[k] = 0.f;

    const float* Sb = S + (size_t)b * 4096 * 4096;

    for (int st = 0; st < 2; st++) {
        float E[4][16];
        #pragma unroll
        for (int r = 0; r < 4; r++) {
            int row = ch * 8 + st * 4 + r;
            const float* Srow = Sb + (size_t)row * 4096 + t * 4;
            float rs = 0.f;
            #pragma unroll
            for (int c = 0; c < 4; c++) {
                float4 x = *(const float4*)(Srow + c * 1024);
                float e0 = __expf(x.x + vr[c].x);
                float e1 = __expf(x.y + vr[c].y);
                float e2 = __expf(x.z + vr[c].z);
                float e3 = __expf(x.w + vr[c].w);
                E[r][c * 4 + 0] = e0; E[r][c * 4 + 1] = e1;
                E[r][c * 4 + 2] = e2; E[r][c * 4 + 3] = e3;
                rs += (e0 + e1) + (e2 + e3);
            }
            part[r * 256 + t] = rs;
        }
        __syncthreads();
        // wave w reduces row w of this stage
        {
            float rs = part[wave * 256 + lane] + part[wave * 256 + 64 + lane]
                     + part[wave * 256 + 128 + lane] + part[wave * 256 + 192 + lane];
            #pragma unroll
            for (int off = 32; off > 0; off >>= 1) rs += __shfl_xor(rs, off, 64);
            if (lane == 0) {
                int row = ch * 8 + st * 4 + wave;
                float un = NORMC - __logf(rs + dtail);
                u[b * UVS + row] = un;
                eu4[wave] = __expf(un);
            }
        }
        __syncthreads();
        float e0 = eu4[0], e1 = eu4[1], e2 = eu4[2], e3 = eu4[3];
        #pragma unroll
        for (int k = 0; k < 16; k++)
            colacc[k] += E[0][k] * e0 + E[1][k] * e1 + E[2][k] * e2 + E[3][k] * e3;
        // no trailing barrier needed: next stage's part writes are ordered by the
        // barrier after its own reduce-phase arrival (all threads passed this stage's
        // reduce reads before the second barrier above).
    }
    float* pp = parts + ((size_t)(b * 512 + ch)) * 4096;
    #pragma unroll
    for (int c = 0; c < 4; c++)
        *(float4*)(pp + c * 1024 + t * 4) =
            make_float4(colacc[c * 4], colacc[c * 4 + 1], colacc[c * 4 + 2], colacc[c * 4 + 3]);
}

// --- 3b) combine column partials (apply e^{-v_old}) -> v[j]; block 16 = dustbin col ---
__global__ __launch_bounds__(256) void sink_vB(
    const float* __restrict__ parts, const float* __restrict__ u,
    float* __restrict__ v, const float* __restrict__ dbp)
{
    int b = blockIdx.z;
    int t = threadIdx.x;
    const float* ub = u + b * UVS;
    float db = dbp[0];
    if (blockIdx.x < 16) {
        int j = blockIdx.x * 256 + t;
        float s = 0.f;
        #pragma unroll 8
        for (int ch = 0; ch < 512; ch++) s += parts[((size_t)(b * 512 + ch)) * 4096 + j];
        float vold = v[b * UVS + j];
        s = s * __expf(-vold) + __expf(db + ub[4096]);   // + dustbin row
        v[b * UVS + j] = NORMC - __logf(s);
    } else {
        __shared__ float red[256];
        float s = 0.f;
        for (int i = t; i < 4096; i += 256) s += __expf(ub[i]);
        red[t] = s; __syncthreads();
        for (int off = 128; off > 0; off >>= 1) {
            if (t < off) red[t] += red[t + off];
            __syncthreads();
        }
        if (t == 0)
            v[b * UVS + 4096] = MLOG2 - __logf(__expf(db) * red[0] + __expf(ub[4096]));
    }
}

// --- 4) per-row top-8: register top-8 of packed keys + in-place element-major merge ---
__global__ __launch_bounds__(256) void topk_kernel(
    const float* __restrict__ S, const float* __restrict__ u, const float* __restrict__ v,
    const float* __restrict__ posA, const float* __restrict__ posB,
    float* __restrict__ tkv, float* __restrict__ tkp, float* __restrict__ dp)
{
    int row = blockIdx.x;             // 0..8191 == b*4096+i
    int b = row >> 12; int i = row & 4095;
    int t = threadIdx.x;
    const float* Srow = S + (size_t)row * 4096;
    const float* vb = v + b * UVS;
    unsigned long long loc[8] = {0,0,0,0,0,0,0,0};
    #pragma unroll
    for (int sblk = 0; sblk < 4; sblk++) {
        int j = sblk * 1024 + t * 4;
        float4 x = *(const float4*)(Srow + j);
        float4 w = *(const float4*)(vb + j);
        float cand[4] = {x.x + w.x, x.y + w.y, x.z + w.z, x.w + w.w};
        #pragma unroll
        for (int e = 0; e < 4; e++) {
            unsigned fb = __float_as_uint(cand[e]);
            fb ^= (fb & 0x80000000u) ? 0xFFFFFFFFu : 0x80000000u;
            unsigned long long key = ((unsigned long long)fb << 32) | (unsigned)(4095 - (j + e));
            if (key > loc[7]) {
                unsigned long long x2 = key;
                #pragma unroll
                for (int rr = 0; rr < 8; rr++) {
                    unsigned long long mx = loc[rr] > x2 ? loc[rr] : x2;
                    unsigned long long mn = loc[rr] > x2 ? x2 : loc[rr];
                    loc[rr] = mx; x2 = mn;
                }
            }
        }
    }
    // element-major single buffer, reg-staged in-place merge (16 KB LDS)
    __shared__ unsigned long long buf[8 * 256];
    #pragma unroll
    for (int rr = 0; rr < 8; rr++) buf[rr * 256 + t] = loc[rr];
    __syncthreads();
    for (int n = 128; n >= 1; n >>= 1) {
        unsigned long long pa[8], pb[8];
        if (t < n) {
            #pragma unroll
            for (int rr = 0; rr < 8; rr++) {
                pa[rr] = buf[rr * 256 + 2 * t];
                pb[rr] = buf[rr * 256 + 2 * t + 1];
            }
        }
        __syncthreads();
        if (t < n) {
            int ia = 0, ib = 0;
            #pragma unroll
            for (int rr = 0; rr < 8; rr++) {
                unsigned long long av = pa[ia], bv = pb[ib];
                bool ta = av >= bv;
                buf[rr * 256 + t] = ta ? av : bv;
                ia += ta; ib += !ta;
            }
        }
        __syncthreads();
    }
    if (t < 8) {
        unsigned long long key = buf[t * 256];
        int idx = 4095 - (int)(key & 0xFFFFFFFFu);
        unsigned fb = (unsigned)(key >> 32);
        fb = (fb & 0x80000000u) ? (fb ^ 0x80000000u) : ~fb;
        float logit = __uint_as_float(fb);
        float val = __expf(logit + u[b * UVS + i]);
        float px = posB[((size_t)(b * 4096 + idx)) * 2 + 0];
        float py = posB[((size_t)(b * 4096 + idx)) * 2 + 1];
        float ax = posA[((size_t)(b * 4096 + i)) * 2 + 0];
        float ay = posA[((size_t)(b * 4096 + i)) * 2 + 1];
        size_t base = ((size_t)(b * 4096 + i)) * 8 + t;
        tkv[base] = val;
        tkp[base * 2 + 0] = px; tkp[base * 2 + 1] = py;
        dp[((size_t)((b * 8 + t) * 2 + 0)) * 4096 + i] = px - ax;
        dp[((size_t)((b * 8 + t) * 2 + 1)) * 4096 + i] = py - ay;
    }
}

// --- 5) geo: 7x7 windowed variance (count_include_pad=False) ---
__global__ __launch_bounds__(256) void geo_kernel(
    const float* __restrict__ dp, float* __restrict__ geo)
{
    int tid = blockIdx.x * 256 + threadIdx.x;   // 65536
    int n = tid & 4095; int bk = tid >> 12;
    int b = bk >> 3; int k = bk & 7;
    int h = n >> 6, w = n & 63;
    const float* dpx = dp + ((size_t)(bk * 2 + 0)) * 4096;
    const float* dpy = dp + ((size_t)(bk * 2 + 1)) * 4096;
    float sx = 0, sy = 0, sxx = 0, syy = 0, cnt = 0;
    #pragma unroll
    for (int dy = -3; dy <= 3; dy++) {
        int hh = h + dy; if ((unsigned)hh >= 64u) continue;
        #pragma unroll
        for (int dx = -3; dx <= 3; dx++) {
            int ww = w + dx; if ((unsigned)ww >= 64u) continue;
            int nn = (hh << 6) + ww;
            float vx = dpx[nn], vy = dpy[nn];
            sx += vx; sy += vy; sxx += vx * vx; syy += vy * vy; cnt += 1.f;
        }
    }
    float inv = 1.f / cnt;
    float mx = sx * inv, my = sy * inv;
    float varx = fmaxf(sxx * inv - mx * mx, 0.f);
    float vary = fmaxf(syy * inv - my * my, 0.f);
    geo[((size_t)(b * 4096 + n)) * 8 + k] = 1.f / (1.f + 100.f * (varx + vary));
}

// --- 6) softmax refine -> refined_warp + conf ---
__global__ __launch_bounds__(256) void refine_kernel(
    const float* __restrict__ tkv, const float* __restrict__ geo,
    const float* __restrict__ tkp, const float* __restrict__ gwp,
    const float* __restrict__ tpp, float* __restrict__ out)
{
    int tid = blockIdx.x * 256 + threadIdx.x;   // 0..8191
    float gw = fminf(fmaxf(gwp[0], 0.f), 2.f);
    float invt = 1.f / tpp[0];
    size_t base = (size_t)tid * 8;
    float cb[8], vv[8];
    float mx = -INFINITY;
    #pragma unroll
    for (int k = 0; k < 8; k++) { vv[k] = tkv[base + k]; cb[k] = vv[k] + gw * geo[base + k]; mx = fmaxf(mx, cb[k]); }
    float e[8], se = 0;
    #pragma unroll
    for (int k = 0; k < 8; k++) { e[k] = __expf((cb[k] - mx) * invt); se += e[k]; }
    float wx = 0, wy = 0, cf = 0; float inv = 1.f / se;
    #pragma unroll
    for (int k = 0; k < 8; k++) {
        float s = e[k] * inv;
        wx += s * tkp[(base + k) * 2 + 0];
        wy += s * tkp[(base + k) * 2 + 1];
        cf += s * vv[k];
    }
    out[(size_t)tid * 2 + 0] = wx;
    out[(size_t)tid * 2 + 1] = wy;
    out[16384 + tid] = cf;
}

// --- 7) weighted affine: 12 sums per batch (double) ---
__global__ __launch_bounds__(256) void affine_reduce(
    const float* __restrict__ posA, const float* __restrict__ out, double* __restrict__ sums)
{
    int b = blockIdx.x; int t = threadIdx.x;
    double acc[12] = {0,0,0,0,0,0,0,0,0,0,0,0};
    for (int n = t; n < 4096; n += 256) {
        size_t idx = (size_t)b * 4096 + n;
        float x = posA[idx * 2], y = posA[idx * 2 + 1];
        float dx = out[idx * 2], dy = out[idx * 2 + 1];
        float c = out[16384 + idx];
        double cd = (double)c;
        double cx = cd * x, cy = cd * y;
        acc[0] += cx * x;  acc[1] += cx * y;  acc[2] += cy * y;
        acc[3] += cx;      acc[4] += cy;      acc[5] += cd;
        acc[6] += cx * dx; acc[7] += cy * dx; acc[8] += cd * dx;
        acc[9] += cx * dy; acc[10] += cy * dy; acc[11] += cd * dy;
    }
    __shared__ double red[256];
    for (int s = 0; s < 12; s++) {
        red[t] = acc[s]; __syncthreads();
        for (int off = 128; off > 0; off >>= 1) {
            if (t < off) red[t] += red[t + off];
            __syncthreads();
        }
        if (t == 0) sums[b * 12 + s] = red[0];
        __syncthreads();
    }
}

// --- 8) closed-form 3x3 solve (AtWA block-diagonal) ---
__global__ void affine_solve(const double* __restrict__ sums, float* __restrict__ out)
{
    int t = threadIdx.x;
    if (t >= 2) return;
    int b = t;
    const double* s = sums + b * 12;
    double den = s[5] > 1e-6 ? s[5] : 1e-6;
    double g00 = s[0] / den + 1e-4, g01 = s[1] / den, g02 = s[3] / den;
    double g11 = s[2] / den + 1e-4, g12 = s[4] / den;
    double g22 = s[5] / den + 1e-4;
    double bx0 = s[6] / den, bx1 = s[7] / den, bx2 = s[8] / den;
    double by0 = s[9] / den, by1 = s[10] / den, by2 = s[11] / den;
    double c00 = g11 * g22 - g12 * g12;
    double c01 = g02 * g12 - g01 * g22;
    double c02 = g01 * g12 - g02 * g11;
    double det = g00 * c00 + g01 * c01 + g02 * c02;
    double id = 1.0 / det;
    double i00 = c00 * id, i01 = c01 * id, i02 = c02 * id;
    double i11 = (g00 * g22 - g02 * g02) * id, i12 = (g01 * g02 - g00 * g12) * id;
    double i22 = (g00 * g11 - g01 * g01) * id;
    double a_ = i00 * bx0 + i01 * bx1 + i02 * bx2;
    double b_ = i01 * bx0 + i11 * bx1 + i12 * bx2;
    double c_ = i02 * bx0 + i12 * bx1 + i22 * bx2;
    double d_ = i00 * by0 + i01 * by1 + i02 * by2;
    double e_ = i01 * by0 + i11 * by1 + i12 * by2;
    double f_ = i02 * by0 + i12 * by1 + i22 * by2;
    float* o = out + 24576 + b * 9;
    o[0] = (float)a_; o[1] = (float)b_; o[2] = (float)c_;
    o[3] = (float)d_; o[4] = (float)e_; o[5] = (float)f_;
    o[6] = 0.f; o[7] = 0.f; o[8] = 1.f;
}

extern "C" void kernel_launch(void* const* d_in, const int* in_sizes, int n_in,
                              void* d_out, int out_size, void* d_ws, size_t ws_size,
                              hipStream_t stream) {
    const float* fA = (const float*)d_in[0];
    const float* fB = (const float*)d_in[1];
    const float* pA = (const float*)d_in[2];
    const float* pB = (const float*)d_in[3];
    const float* db = (const float*)d_in[4];
    const float* gw = (const float*)d_in[5];
    const float* tp = (const float*)d_in[6];

    float* ws    = (float*)d_ws;
    float* out   = (float*)d_out;
    float* S     = ws;
    float* u     = ws + OFF_U;
    float* v     = ws + OFF_V;
    float* rn    = ws + OFF_RN;
    float* parts = ws + OFF_PARTS;
    float* tkv   = ws + OFF_TKV;
    float* tkp   = ws + OFF_TKP;
    float* dp    = ws + OFF_DP;
    float* geo   = ws + OFF_GEO;
    double* sums = (double*)(ws + OFF_SUM);

    // zero u and v (contiguous; v must be 0 at iteration 1)
    hipMemsetAsync(u, 0, (size_t)(4 * UVS) * sizeof(float), stream);

    norms_kernel<<<4096, 256, 0, stream>>>(fA, fB, rn);
    gemm_mfma<<<dim3(64, 64, 2), 256, 0, stream>>>(fA, fB, rn, tp, S);

    for (int it = 0; it < 5; it++) {
        sink_fused<<<dim3(512, 1, 2), 256, 0, stream>>>(S, u, v, db, parts);
        sink_vB<<<dim3(17, 1, 2), 256, 0, stream>>>(parts, u, v, db);
    }

    topk_kernel<<<8192, 256, 0, stream>>>(S, u, v, pA, pB, tkv, tkp, dp);
    geo_kernel<<<256, 256, 0, stream>>>(dp, geo);
    refine_kernel<<<32, 256, 0, stream>>>(tkv, geo, tkp, gw, tp, out);
    affine_reduce<<<2, 256, 0, stream>>>(pA, out, sums);
    affine_solve<<<1, 64, 0, stream>>>(sums, out);
}

// Round 6
// 413.100 us; speedup vs baseline: 1.2270x; 1.2270x over previous
//
#include <hip/hip_runtime.h>
#include <math.h>

// B=2, H=W=64, N=4096, C=128, K=8, 5 Sinkhorn iters.
// Workspace holds E0 = exp(S) (fp32, selection-safe); duals kept as w=e^v, z=e^u.
#define UVS 4104   // padded dual-array batch stride (float4-aligned)

// Workspace layout (float offsets)
#define OFF_ZU    33554432ul               // 2*4096*4096 floats of E0 first
#define OFF_WV    (OFF_ZU + 2*UVS)
#define OFF_RN    (OFF_WV + 2*UVS)         // 16384 (rnA | rnB)
#define OFF_PARTS (OFF_RN + 16384)         // 2*256*4096 column partial sums
#define OFF_TKV   (OFF_PARTS + 2097152)    // 2*4096*8
#define OFF_TKP   (OFF_TKV + 65536)        // 2*4096*8*2
#define OFF_DP    (OFF_TKP + 131072)       // 2*8*2*4096 planar
#define OFF_GEO   (OFF_DP + 131072)        // 2*4096*8
#define OFF_SUM   (OFF_GEO + 65536)        // 24 doubles

#define EXPC    0.0001220703125f           // e^NORMC = 1/8192
#define HALFC   0.5f                       // e^{log(N)+NORMC} = 1/2

typedef __attribute__((ext_vector_type(8))) short bf16x8;
typedef __attribute__((ext_vector_type(4))) float f32x4;

static __device__ __forceinline__ unsigned f2bf(float x) {  // RTNE fp32->bf16 bits
    unsigned u = __float_as_uint(x);
    return (u + 0x7FFFu + ((u >> 16) & 1u)) >> 16;
}
static __device__ __forceinline__ float bf2f(unsigned h) { return __uint_as_float(h << 16); }

// --- 0) init duals: w = e^0 = 1 everywhere (incl. dustbin) ---
__global__ __launch_bounds__(256) void init_kernel(float* __restrict__ wv)
{
    int i = blockIdx.x * 256 + threadIdx.x;
    if (i < 2 * UVS) wv[i] = 1.0f;
}

// --- 1) inverse L2 norms ---
__global__ __launch_bounds__(256) void norms_kernel(
    const float* __restrict__ fA, const float* __restrict__ fB, float* __restrict__ rn)
{
    int t = threadIdx.x;
    int rowg = blockIdx.x * 4 + (t >> 6);
    int lane = t & 63;
    const float* f = (rowg < 8192) ? fA : fB;
    int r = rowg & 8191;
    float x0 = f[(size_t)r * 128 + lane];
    float x1 = f[(size_t)r * 128 + 64 + lane];
    float s = x0 * x0 + x1 * x1;
    #pragma unroll
    for (int off = 32; off > 0; off >>= 1) s += __shfl_xor(s, off, 64);
    if (lane == 0) rn[rowg] = 1.f / fmaxf(sqrtf(s), 1e-12f);
}

// --- 2) E0 = exp((fA.fB^T)*rnA*rnB/temp) via bf16 hi/lo-split MFMA ---
#define LDK 72
__global__ __launch_bounds__(256) void gemm_mfma(
    const float* __restrict__ fA, const float* __restrict__ fB,
    const float* __restrict__ rn, const float* __restrict__ temp,
    float* __restrict__ E0)
{
    __shared__ short Ahi[64 * LDK], Alo[64 * LDK], Bhi[64 * LDK], Blo[64 * LDK];
    int b = blockIdx.z;
    int i0 = blockIdx.y * 64, j0 = blockIdx.x * 64;
    int t = threadIdx.x;
    int r = t >> 2;
    int c0 = (t & 3) * 16;
    int wave = t >> 6, lane = t & 63;
    int fr = lane & 15;
    int quad = lane >> 4;
    f32x4 acc[4] = {f32x4{0,0,0,0}, f32x4{0,0,0,0}, f32x4{0,0,0,0}, f32x4{0,0,0,0}};

    const float* pa0 = fA + ((size_t)(b * 4096 + i0 + r)) * 128 + c0;
    const float* pb0 = fB + ((size_t)(b * 4096 + j0 + r)) * 128 + c0;

    for (int ks = 0; ks < 2; ks++) {
        float4 a4[4], b4[4];
        #pragma unroll
        for (int q = 0; q < 4; q++) {
            a4[q] = *(const float4*)(pa0 + ks * 64 + q * 4);
            b4[q] = *(const float4*)(pb0 + ks * 64 + q * 4);
        }
        __syncthreads();
        #pragma unroll
        for (int q = 0; q < 4; q++) {
            float xv[4] = {a4[q].x, a4[q].y, a4[q].z, a4[q].w};
            unsigned h[4], l[4];
            #pragma unroll
            for (int e = 0; e < 4; e++) { h[e] = f2bf(xv[e]); l[e] = f2bf(xv[e] - bf2f(h[e])); }
            *(uint2*)&Ahi[r * LDK + c0 + q * 4] = make_uint2(h[0] | (h[1] << 16), h[2] | (h[3] << 16));
            *(uint2*)&Alo[r * LDK + c0 + q * 4] = make_uint2(l[0] | (l[1] << 16), l[2] | (l[3] << 16));
            float yv[4] = {b4[q].x, b4[q].y, b4[q].z, b4[q].w};
            #pragma unroll
            for (int e = 0; e < 4; e++) { h[e] = f2bf(yv[e]); l[e] = f2bf(yv[e] - bf2f(h[e])); }
            *(uint2*)&Bhi[r * LDK + c0 + q * 4] = make_uint2(h[0] | (h[1] << 16), h[2] | (h[3] << 16));
            *(uint2*)&Blo[r * LDK + c0 + q * 4] = make_uint2(l[0] | (l[1] << 16), l[2] | (l[3] << 16));
        }
        __syncthreads();
        #pragma unroll
        for (int kk = 0; kk < 2; kk++) {
            int koff = kk * 32 + quad * 8;
            bf16x8 ah = *(const bf16x8*)&Ahi[(wave * 16 + fr) * LDK + koff];
            bf16x8 al = *(const bf16x8*)&Alo[(wave * 16 + fr) * LDK + koff];
            #pragma unroll
            for (int nb = 0; nb < 4; nb++) {
                bf16x8 bh = *(const bf16x8*)&Bhi[(nb * 16 + fr) * LDK + koff];
                bf16x8 bl = *(const bf16x8*)&Blo[(nb * 16 + fr) * LDK + koff];
                acc[nb] = __builtin_amdgcn_mfma_f32_16x16x32_bf16(ah, bh, acc[nb], 0, 0, 0);
                acc[nb] = __builtin_amdgcn_mfma_f32_16x16x32_bf16(al, bh, acc[nb], 0, 0, 0);
                acc[nb] = __builtin_amdgcn_mfma_f32_16x16x32_bf16(ah, bl, acc[nb], 0, 0, 0);
            }
        }
    }
    float invt = 1.f / temp[0];
    int m0 = i0 + wave * 16 + quad * 4;
    float ra[4];
    #pragma unroll
    for (int rr = 0; rr < 4; rr++) ra[rr] = rn[b * 4096 + m0 + rr] * invt;
    #pragma unroll
    for (int nb = 0; nb < 4; nb++) {
        int col = j0 + nb * 16 + fr;
        float rbv = rn[8192 + b * 4096 + col];
        #pragma unroll
        for (int rr = 0; rr < 4; rr++)
            E0[((size_t)(b * 4096 + m0 + rr)) * 4096 + col] = __expf(acc[nb][rr] * (ra[rr] * rbv));
    }
}

// --- 3) fused Sinkhorn iteration (R4 structure, exp/log-free inner loops) ---
// grid (256 chunks, 1, 2); block 256 = 4 waves; chunk = 16 rows (4 stages x 4 rows).
// q_ij = E0_ij * w_j staged in LDS; z_i = (1/8192)/(rowsum_i + e^db*w_N);
// col partial A_j = sum_i q_ij*z_i  (true colsum = A_j / w_j, applied in sink_vB).
__global__ __launch_bounds__(256) void sink_fused(
    const float* __restrict__ E0, float* __restrict__ zu, const float* __restrict__ wv,
    const float* __restrict__ dbp, float* __restrict__ parts)
{
    int b = blockIdx.z;
    int ch = blockIdx.x;
    int t = threadIdx.x;
    int wave = t >> 6, lane = t & 63;
    const float* wb = wv + b * UVS;
    float edb = __expf(dbp[0]);
    __shared__ float Sch[4 * 4096];   // 64 KB stage buffer (q values)
    __shared__ float z4[4];

    // chunk 0 refreshes the dustbin-row dual: zuN = 0.5 / (e^db * sum_j w_j + w_N)
    if (ch == 0) {
        __shared__ float red[256];
        float sv = 0.f;
        #pragma unroll
        for (int k = 0; k < 16; k++) sv += wb[t + k * 256];
        red[t] = sv; __syncthreads();
        for (int off = 128; off > 0; off >>= 1) {
            if (t < off) red[t] += red[t + off];
            __syncthreads();
        }
        if (t == 0) zu[b * UVS + 4096] = HALFC / (edb * red[0] + wb[4096]);
        __syncthreads();
    }

    float dtail = edb * wb[4096];
    float colacc[16];
    #pragma unroll
    for (int k = 0; k < 16; k++) colacc[k] = 0.f;

    const float* Eb = E0 + (size_t)b * 4096 * 4096;

    for (int st = 0; st < 4; st++) {
        int row = ch * 16 + st * 4 + wave;
        const float* Erow = Eb + (size_t)row * 4096;
        float rs = 0.f;
        #pragma unroll
        for (int c = 0; c < 16; c++) {
            int j = lane * 4 + c * 256;
            float4 x = *(const float4*)(Erow + j);
            float4 w = *(const float4*)(wb + j);
            float4 q = make_float4(x.x * w.x, x.y * w.y, x.z * w.z, x.w * w.w);
            *(float4*)&Sch[wave * 4096 + j] = q;
            rs += (q.x + q.y) + (q.z + q.w);
        }
        #pragma unroll
        for (int off = 32; off > 0; off >>= 1) rs += __shfl_xor(rs, off, 64);
        if (lane == 0) {
            float zi = EXPC / (rs + dtail);
            zu[b * UVS + row] = zi;
            z4[wave] = zi;
        }
        __syncthreads();
        float z0 = z4[0], z1 = z4[1], z2 = z4[2], z3 = z4[3];
        #pragma unroll
        for (int k = 0; k < 16; k++) {
            int c = t + k * 256;
            colacc[k] += Sch[c] * z0 + Sch[4096 + c] * z1
                       + Sch[8192 + c] * z2 + Sch[12288 + c] * z3;
        }
        __syncthreads();   // protect Sch/z4 before next stage
    }
    float* pp = parts + ((size_t)(b * 256 + ch)) * 4096;
    #pragma unroll
    for (int k = 0; k < 16; k++) pp[t + k * 256] = colacc[k];
}

// --- 3b) combine column partials -> w_new[j]; block 16 handles dustbin column ---
__global__ __launch_bounds__(256) void sink_vB(
    const float* __restrict__ parts, const float* __restrict__ zu,
    float* __restrict__ wv, const float* __restrict__ dbp)
{
    int b = blockIdx.z;
    int t = threadIdx.x;
    float edb = __expf(dbp[0]);
    if (blockIdx.x < 16) {
        int j = blockIdx.x * 256 + t;
        float s = 0.f;
        #pragma unroll 16
        for (int ch = 0; ch < 256; ch++) s += parts[((size_t)(b * 256 + ch)) * 4096 + j];
        float wold = wv[b * UVS + j];
        float total = s / wold + edb * zu[b * UVS + 4096];   // + dustbin row
        wv[b * UVS + j] = EXPC / total;                      // w = e^{v_new}
    } else {
        __shared__ float red[256];
        float s = 0.f;
        for (int i = t; i < 4096; i += 256) s += zu[b * UVS + i];
        red[t] = s; __syncthreads();
        for (int off = 128; off > 0; off >>= 1) {
            if (t < off) red[t] += red[t + off];
            __syncthreads();
        }
        if (t == 0)
            wv[b * UVS + 4096] = HALFC / (edb * red[0] + zu[b * UVS + 4096]);
    }
}

// --- 4) per-row top-8 of E0*w (positive: raw-bit order == S+v order) ---
// R4 merge: element-major ping/pong LDS, dynamic LDS indexing (no reg indexing).
__global__ __launch_bounds__(256) void topk_kernel(
    const float* __restrict__ E0, const float* __restrict__ zu, const float* __restrict__ wv,
    const float* __restrict__ posA, const float* __restrict__ posB,
    float* __restrict__ tkv, float* __restrict__ tkp, float* __restrict__ dp)
{
    int row = blockIdx.x;             // 0..8191 == b*4096+i
    int b = row >> 12; int i = row & 4095;
    int t = threadIdx.x;
    const float* Erow = E0 + (size_t)row * 4096;
    const float* wb = wv + b * UVS;
    unsigned long long loc[8] = {0,0,0,0,0,0,0,0};
    #pragma unroll
    for (int sblk = 0; sblk < 4; sblk++) {
        int j = sblk * 1024 + t * 4;
        float4 x = *(const float4*)(Erow + j);
        float4 w = *(const float4*)(wb + j);
        float cand[4] = {x.x * w.x, x.y * w.y, x.z * w.z, x.w * w.w};
        #pragma unroll
        for (int e = 0; e < 4; e++) {
            unsigned fb = __float_as_uint(cand[e]);   // positive floats: bits are monotone
            unsigned long long key = ((unsigned long long)fb << 32) | (unsigned)(4095 - (j + e));
            if (key > loc[7]) {
                unsigned long long x2 = key;
                #pragma unroll
                for (int rr = 0; rr < 8; rr++) {
                    unsigned long long mx = loc[rr] > x2 ? loc[rr] : x2;
                    unsigned long long mn = loc[rr] > x2 ? x2 : loc[rr];
                    loc[rr] = mx; x2 = mn;
                }
            }
        }
    }
    __shared__ unsigned long long ping[8 * 256];
    __shared__ unsigned long long pong[8 * 256];
    #pragma unroll
    for (int rr = 0; rr < 8; rr++) ping[rr * 256 + t] = loc[rr];
    __syncthreads();
    unsigned long long* a = ping;
    unsigned long long* c = pong;
    for (int n = 128; n >= 1; n >>= 1) {
        if (t < n) {
            int ia = 0, ib = 0;
            unsigned long long outm[8];
            #pragma unroll
            for (int rr = 0; rr < 8; rr++) {
                unsigned long long av = a[ia * 256 + 2 * t];
                unsigned long long bv = a[ib * 256 + 2 * t + 1];
                bool ta = av >= bv;
                outm[rr] = ta ? av : bv;
                ia += ta; ib += !ta;
            }
            #pragma unroll
            for (int rr = 0; rr < 8; rr++) c[rr * 256 + t] = outm[rr];
        }
        __syncthreads();
        unsigned long long* tmp = a; a = c; c = tmp;
    }
    if (t < 8) {
        unsigned long long key = a[t * 256];
        int idx = 4095 - (int)(key & 0xFFFFFFFFu);
        float cand = __uint_as_float((unsigned)(key >> 32));
        float val = cand * zu[b * UVS + i];          // p = E0*w*z
        float px = posB[((size_t)(b * 4096 + idx)) * 2 + 0];
        float py = posB[((size_t)(b * 4096 + idx)) * 2 + 1];
        float ax = posA[((size_t)(b * 4096 + i)) * 2 + 0];
        float ay = posA[((size_t)(b * 4096 + i)) * 2 + 1];
        size_t base = ((size_t)(b * 4096 + i)) * 8 + t;
        tkv[base] = val;
        tkp[base * 2 + 0] = px; tkp[base * 2 + 1] = py;
        dp[((size_t)((b * 8 + t) * 2 + 0)) * 4096 + i] = px - ax;
        dp[((size_t)((b * 8 + t) * 2 + 1)) * 4096 + i] = py - ay;
    }
}

// --- 5) geo: 7x7 windowed variance (count_include_pad=False) ---
__global__ __launch_bounds__(256) void geo_kernel(
    const float* __restrict__ dp, float* __restrict__ geo)
{
    int tid = blockIdx.x * 256 + threadIdx.x;   // 65536
    int n = tid & 4095; int bk = tid >> 12;
    int b = bk >> 3; int k = bk & 7;
    int h = n >> 6, w = n & 63;
    const float* dpx = dp + ((size_t)(bk * 2 + 0)) * 4096;
    const float* dpy = dp + ((size_t)(bk * 2 + 1)) * 4096;
    float sx = 0, sy = 0, sxx = 0, syy = 0, cnt = 0;
    #pragma unroll
    for (int dy = -3; dy <= 3; dy++) {
        int hh = h + dy; if ((unsigned)hh >= 64u) continue;
        #pragma unroll
        for (int dx = -3; dx <= 3; dx++) {
            int ww = w + dx; if ((unsigned)ww >= 64u) continue;
            int nn = (hh << 6) + ww;
            float vx = dpx[nn], vy = dpy[nn];
            sx += vx; sy += vy; sxx += vx * vx; syy += vy * vy; cnt += 1.f;
        }
    }
    float inv = 1.f / cnt;
    float mx = sx * inv, my = sy * inv;
    float varx = fmaxf(sxx * inv - mx * mx, 0.f);
    float vary = fmaxf(syy * inv - my * my, 0.f);
    geo[((size_t)(b * 4096 + n)) * 8 + k] = 1.f / (1.f + 100.f * (varx + vary));
}

// --- 6) softmax refine -> refined_warp + conf ---
__global__ __launch_bounds__(256) void refine_kernel(
    const float* __restrict__ tkv, const float* __restrict__ geo,
    const float* __restrict__ tkp, const float* __restrict__ gwp,
    const float* __restrict__ tpp, float* __restrict__ out)
{
    int tid = blockIdx.x * 256 + threadIdx.x;   // 0..8191
    float gw = fminf(fmaxf(gwp[0], 0.f), 2.f);
    float invt = 1.f / tpp[0];
    size_t base = (size_t)tid * 8;
    float cb[8], vv[8];
    float mx = -INFINITY;
    #pragma unroll
    for (int k = 0; k < 8; k++) { vv[k] = tkv[base + k]; cb[k] = vv[k] + gw * geo[base + k]; mx = fmaxf(mx, cb[k]); }
    float e[8], se = 0;
    #pragma unroll
    for (int k = 0; k < 8; k++) { e[k] = __expf((cb[k] - mx) * invt); se += e[k]; }
    float wx = 0, wy = 0, cf = 0; float inv = 1.f / se;
    #pragma unroll
    for (int k = 0; k < 8; k++) {
        float s = e[k] * inv;
        wx += s * tkp[(base + k) * 2 + 0];
        wy += s * tkp[(base + k) * 2 + 1];
        cf += s * vv[k];
    }
    out[(size_t)tid * 2 + 0] = wx;
    out[(size_t)tid * 2 + 1] = wy;
    out[16384 + tid] = cf;
}

// --- 7) weighted affine: 12 sums per batch (double) ---
__global__ __launch_bounds__(256) void affine_reduce(
    const float* __restrict__ posA, const float* __restrict__ out, double* __restrict__ sums)
{
    int b = blockIdx.x; int t = threadIdx.x;
    double acc[12] = {0,0,0,0,0,0,0,0,0,0,0,0};
    for (int n = t; n < 4096; n += 256) {
        size_t idx = (size_t)b * 4096 + n;
        float x = posA[idx * 2], y = posA[idx * 2 + 1];
        float dx = out[idx * 2], dy = out[idx * 2 + 1];
        float c = out[16384 + idx];
        double cd = (double)c;
        double cx = cd * x, cy = cd * y;
        acc[0] += cx * x;  acc[1] += cx * y;  acc[2] += cy * y;
        acc[3] += cx;      acc[4] += cy;      acc[5] += cd;
        acc[6] += cx * dx; acc[7] += cy * dx; acc[8] += cd * dx;
        acc[9] += cx * dy; acc[10] += cy * dy; acc[11] += cd * dy;
    }
    __shared__ double red[256];
    for (int s = 0; s < 12; s++) {
        red[t] = acc[s]; __syncthreads();
        for (int off = 128; off > 0; off >>= 1) {
            if (t < off) red[t] += red[t + off];
            __syncthreads();
        }
        if (t == 0) sums[b * 12 + s] = red[0];
        __syncthreads();
    }
}

// --- 8) closed-form 3x3 solve (AtWA block-diagonal) ---
__global__ void affine_solve(const double* __restrict__ sums, float* __restrict__ out)
{
    int t = threadIdx.x;
    if (t >= 2) return;
    int b = t;
    const double* s = sums + b * 12;
    double den = s[5] > 1e-6 ? s[5] : 1e-6;
    double g00 = s[0] / den + 1e-4, g01 = s[1] / den, g02 = s[3] / den;
    double g11 = s[2] / den + 1e-4, g12 = s[4] / den;
    double g22 = s[5] / den + 1e-4;
    double bx0 = s[6] / den, bx1 = s[7] / den, bx2 = s[8] / den;
    double by0 = s[9] / den, by1 = s[10] / den, by2 = s[11] / den;
    double c00 = g11 * g22 - g12 * g12;
    double c01 = g02 * g12 - g01 * g22;
    double c02 = g01 * g12 - g02 * g11;
    double det = g00 * c00 + g01 * c01 + g02 * c02;
    double id = 1.0 / det;
    double i00 = c00 * id, i01 = c01 * id, i02 = c02 * id;
    double i11 = (g00 * g22 - g02 * g02) * id, i12 = (g01 * g02 - g00 * g12) * id;
    double i22 = (g00 * g11 - g01 * g01) * id;
    double a_ = i00 * bx0 + i01 * bx1 + i02 * bx2;
    double b_ = i01 * bx0 + i11 * bx1 + i12 * bx2;
    double c_ = i02 * bx0 + i12 * bx1 + i22 * bx2;
    double d_ = i00 * by0 + i01 * by1 + i02 * by2;
    double e_ = i01 * by0 + i11 * by1 + i12 * by2;
    double f_ = i02 * by0 + i12 * by1 + i22 * by2;
    float* o = out + 24576 + b * 9;
    o[0] = (float)a_; o[1] = (float)b_; o[2] = (float)c_;
    o[3] = (float)d_; o[4] = (float)e_; o[5] = (float)f_;
    o[6] = 0.f; o[7] = 0.f; o[8] = 1.f;
}

extern "C" void kernel_launch(void* const* d_in, const int* in_sizes, int n_in,
                              void* d_out, int out_size, void* d_ws, size_t ws_size,
                              hipStream_t stream) {
    const float* fA = (const float*)d_in[0];
    const float* fB = (const float*)d_in[1];
    const float* pA = (const float*)d_in[2];
    const float* pB = (const float*)d_in[3];
    const float* db = (const float*)d_in[4];
    const float* gw = (const float*)d_in[5];
    const float* tp = (const float*)d_in[6];

    float* ws    = (float*)d_ws;
    float* out   = (float*)d_out;
    float* E0    = ws;
    float* zu    = ws + OFF_ZU;
    float* wv    = ws + OFF_WV;
    float* rn    = ws + OFF_RN;
    float* parts = ws + OFF_PARTS;
    float* tkv   = ws + OFF_TKV;
    float* tkp   = ws + OFF_TKP;
    float* dp    = ws + OFF_DP;
    float* geo   = ws + OFF_GEO;
    double* sums = (double*)(ws + OFF_SUM);

    init_kernel<<<33, 256, 0, stream>>>(wv);                 // w = e^0 = 1
    norms_kernel<<<4096, 256, 0, stream>>>(fA, fB, rn);
    gemm_mfma<<<dim3(64, 64, 2), 256, 0, stream>>>(fA, fB, rn, tp, E0);

    for (int it = 0; it < 5; it++) {
        sink_fused<<<dim3(256, 1, 2), 256, 0, stream>>>(E0, zu, wv, db, parts);
        sink_vB<<<dim3(17, 1, 2), 256, 0, stream>>>(parts, zu, wv, db);
    }

    topk_kernel<<<8192, 256, 0, stream>>>(E0, zu, wv, pA, pB, tkv, tkp, dp);
    geo_kernel<<<256, 256, 0, stream>>>(dp, geo);
    refine_kernel<<<32, 256, 0, stream>>>(tkv, geo, tkp, gw, tp, out);
    affine_reduce<<<2, 256, 0, stream>>>(pA, out, sums);
    affine_solve<<<1, 64, 0, stream>>>(sums, out);
}